// Round 3
// baseline (29376.614 us; speedup 1.0000x reference)
//
#include <hip/hip_runtime.h>
#include <math.h>

// KNNGraph(2) on N=16384 points, D=64, fp32.
// adjacency = I + one-hot(nearest other neighbor) per row.
// argmin_j (sq[j] - 2*dot(x_i,x_j)), j != i  (sq[i] term is row-constant).
//
// R1 lesson: zero-filling the 1-GiB output from inside the compute kernel's
// barriered loop caused 64 GB of HBM traffic (store-drain at every
// __syncthreads + RFO amplification) -> 26.9 ms. Decouple: streaming NT
// zero-fill kernel + store-free compute kernel.
// R2 lesson: __builtin_nontemporal_store needs a clang ext_vector_type,
// not HIP's struct float4.

#define NPTS 16384
#define DIM 64
#define BM 128          // rows per block
#define BN 64           // cols per j-tile
#define TM 8            // rows per thread
#define TN 4            // cols per thread
#define NTHR 256        // 16x16 thread layout
#define JSPLIT 4        // split j-range: 512 blocks, all co-resident
#define JRANGE (NPTS / JSPLIT)   // 4096
#define NJT (JRANGE / BN)        // 64 tiles
#define LS 68           // LDS row stride in floats: 272 B = 16B aligned, bank-spread

typedef float floatx4 __attribute__((ext_vector_type(4)));

// ---- 1 GiB zero-fill: contiguous nontemporal 16B stores ----
// 4 stores per thread, fully coalesced: block b covers [b*1024, b*1024+1024) float4s.
__global__ void zero_kernel(floatx4* __restrict__ out) {
  size_t base = (size_t)blockIdx.x * 1024 + threadIdx.x;
  const floatx4 z = {0.f, 0.f, 0.f, 0.f};
#pragma unroll
  for (int k = 0; k < 4; ++k)
    __builtin_nontemporal_store(z, &out[base + 256 * k]);
}

__global__ void sq_kernel(const float* __restrict__ X, float* __restrict__ sqout) {
  int i = blockIdx.x * NTHR + threadIdx.x;
  const float4* x4 = (const float4*)(X + (size_t)i * DIM);
  float s = 0.f;
#pragma unroll
  for (int k = 0; k < DIM / 4; ++k) {
    float4 v = x4[k];
    s = fmaf(v.x, v.x, s); s = fmaf(v.y, v.y, s);
    s = fmaf(v.z, v.z, s); s = fmaf(v.w, v.w, s);
  }
  sqout[i] = s;
}

__global__ __launch_bounds__(NTHR, 3) void knn_kernel(
    const float* __restrict__ X, const float* __restrict__ sqn,
    float* __restrict__ cand_val, int* __restrict__ cand_idx) {
  __shared__ float As[BM * LS];   // 34816 B
  __shared__ float Bs[BN * LS];   // 17408 B
  __shared__ float sqt[BN];

  const int tid = threadIdx.x;
  const int tx = tid & 15;
  const int ty = tid >> 4;
  const int ib = blockIdx.x >> 2;   // / JSPLIT
  const int jh = blockIdx.x & 3;    // % JSPLIT
  const int i0 = ib * BM;
  const int j0base = jh * JRANGE;

  // Stage A tile (BM x DIM) once: coalesced float4 loads.
  {
    const float4* src = (const float4*)(X + (size_t)i0 * DIM);
#pragma unroll
    for (int p = 0; p < (BM * DIM / 4) / NTHR; ++p) {
      int f4 = tid + NTHR * p;
      int r = f4 >> 4, c = f4 & 15;   // 16 float4 per row
      float4 v = src[f4];
      *(float4*)(&As[r * LS + c * 4]) = v;
    }
  }

  float bestv[TM];
  int besti[TM];
#pragma unroll
  for (int mk = 0; mk < TM; ++mk) { bestv[mk] = INFINITY; besti[mk] = 0x7fffffff; }

  for (int jt = 0; jt < NJT; ++jt) {
    const int j0 = j0base + jt * BN;
    __syncthreads();   // protect Bs from previous iteration's readers
    // Stage B tile (BN x DIM)
    {
      const float4* src = (const float4*)(X + (size_t)j0 * DIM);
#pragma unroll
      for (int p = 0; p < (BN * DIM / 4) / NTHR; ++p) {
        int f4 = tid + NTHR * p;
        int r = f4 >> 4, c = f4 & 15;
        float4 v = src[f4];
        *(float4*)(&Bs[r * LS + c * 4]) = v;
      }
      if (tid < BN) sqt[tid] = sqn[j0 + tid];
    }
    __syncthreads();

    float acc[TM][TN];
#pragma unroll
    for (int mk = 0; mk < TM; ++mk)
#pragma unroll
      for (int nk = 0; nk < TN; ++nk) acc[mk][nk] = 0.f;

#pragma unroll
    for (int d0 = 0; d0 < DIM; d0 += 4) {
      float4 a[TM], b[TN];
#pragma unroll
      for (int mk = 0; mk < TM; ++mk)
        a[mk] = *(const float4*)(&As[(ty + 16 * mk) * LS + d0]);
#pragma unroll
      for (int nk = 0; nk < TN; ++nk)
        b[nk] = *(const float4*)(&Bs[(tx + 16 * nk) * LS + d0]);
#pragma unroll
      for (int mk = 0; mk < TM; ++mk)
#pragma unroll
        for (int nk = 0; nk < TN; ++nk) {
          acc[mk][nk] = fmaf(a[mk].x, b[nk].x, acc[mk][nk]);
          acc[mk][nk] = fmaf(a[mk].y, b[nk].y, acc[mk][nk]);
          acc[mk][nk] = fmaf(a[mk].z, b[nk].z, acc[mk][nk]);
          acc[mk][nk] = fmaf(a[mk].w, b[nk].w, acc[mk][nk]);
        }
    }

    // Update running argmin (j visited in increasing order per thread).
#pragma unroll
    for (int nk = 0; nk < TN; ++nk) {
      const int j = j0 + tx + 16 * nk;
      const float sj = sqt[tx + 16 * nk];
#pragma unroll
      for (int mk = 0; mk < TM; ++mk) {
        const int irow = i0 + ty + 16 * mk;
        float v = fmaf(-2.f, acc[mk][nk], sj);
        if (j != irow && (v < bestv[mk] || (v == bestv[mk] && j < besti[mk]))) {
          bestv[mk] = v;
          besti[mk] = j;
        }
      }
    }
  }

  // Cross-thread reduction: row m is owned by the 16 tx-threads of its ty.
  __syncthreads();
  float* rv = As;        // [BM][16] floats (8 KB, fits in As)
  int* ri = (int*)Bs;    // [BM][16] ints  (8 KB, fits in Bs)
#pragma unroll
  for (int mk = 0; mk < TM; ++mk) {
    int m = ty + 16 * mk;
    rv[m * 16 + tx] = bestv[mk];
    ri[m * 16 + tx] = besti[mk];
  }
  __syncthreads();
  if (tid < BM) {
    float bv = INFINITY;
    int bi = 0x7fffffff;
#pragma unroll
    for (int t = 0; t < 16; ++t) {
      float v = rv[tid * 16 + t];
      int ix = ri[tid * 16 + t];
      if (v < bv || (v == bv && ix < bi)) { bv = v; bi = ix; }
    }
    cand_val[(size_t)(i0 + tid) * JSPLIT + jh] = bv;
    cand_idx[(size_t)(i0 + tid) * JSPLIT + jh] = bi;
  }
}

__global__ void merge_kernel(const float* __restrict__ cand_val,
                             const int* __restrict__ cand_idx,
                             float* __restrict__ out) {
  int i = blockIdx.x * NTHR + threadIdx.x;
  float bv = INFINITY;
  int bi = 0x7fffffff;
#pragma unroll
  for (int s = 0; s < JSPLIT; ++s) {
    float v = cand_val[(size_t)i * JSPLIT + s];
    int ix = cand_idx[(size_t)i * JSPLIT + s];
    if (v < bv || (v == bv && ix < bi)) { bv = v; bi = ix; }
  }
  out[(size_t)i * NPTS + i] = 1.0f;   // self is always nearest (dist ~ 0)
  out[(size_t)i * NPTS + bi] = 1.0f;  // nearest other neighbor
}

extern "C" void kernel_launch(void* const* d_in, const int* in_sizes, int n_in,
                              void* d_out, int out_size, void* d_ws, size_t ws_size,
                              hipStream_t stream) {
  const float* X = (const float*)d_in[0];
  float* out = (float*)d_out;

  // Workspace layout: sq[N] | cand_val[N*JSPLIT] | cand_idx[N*JSPLIT]  (~576 KB)
  float* sq = (float*)d_ws;
  float* cand_val = sq + NPTS;
  int* cand_idx = (int*)(cand_val + (size_t)NPTS * JSPLIT);

  // 16384^2 floats = 67,108,864 float4 = 65536 blocks x 256 threads x 4 stores.
  zero_kernel<<<65536, NTHR, 0, stream>>>((floatx4*)out);
  sq_kernel<<<NPTS / NTHR, NTHR, 0, stream>>>(X, sq);
  knn_kernel<<<(NPTS / BM) * JSPLIT, NTHR, 0, stream>>>(X, sq, cand_val, cand_idx);
  merge_kernel<<<NPTS / NTHR, NTHR, 0, stream>>>(cand_val, cand_idx, out);
}

// Round 4
// 27296.973 us; speedup vs baseline: 1.0762x; 1.0762x over previous
//
#include <hip/hip_runtime.h>
#include <math.h>

// KNNGraph(2) on N=16384 points, D=64, fp32.
// adjacency = I + one-hot(nearest other neighbor) per row.
// argmin_j (sq[j] - 2*dot(x_i,x_j)), j != i  (sq[i] term is row-constant).
//
// R1/R3 lesson: the 26-29 ms was NOT output-store traffic. knn_kernel with no
// output stores still produced 78 GB of HBM traffic at VALUBusy 1.7% ->
// register-tile spill to scratch (TM=8 float4 operands ~96+ live VGPRs).
// R4: shrink register tile (TM=TN=4, BM=BN=64), no __launch_bounds__, so the
// whole working set stays in VGPRs.

#define NPTS 16384
#define DIM 64
#define BM 64           // rows per block
#define BN 64           // cols per j-tile
#define TM 4            // rows per thread
#define TN 4            // cols per thread
#define NTHR 256        // 16x16 thread layout
#define JSPLIT 4        // split j-range: 1024 blocks = 4 blocks/CU
#define JRANGE (NPTS / JSPLIT)   // 4096
#define NJT (JRANGE / BN)        // 64 tiles
#define LS 68           // LDS row stride in floats: 272 B = 16B aligned, bank-spread

typedef float floatx4 __attribute__((ext_vector_type(4)));

// ---- 1 GiB zero-fill: contiguous nontemporal 16B stores ----
__global__ void zero_kernel(floatx4* __restrict__ out) {
  size_t base = (size_t)blockIdx.x * 1024 + threadIdx.x;
  const floatx4 z = {0.f, 0.f, 0.f, 0.f};
#pragma unroll
  for (int k = 0; k < 4; ++k)
    __builtin_nontemporal_store(z, &out[base + 256 * k]);
}

__global__ void sq_kernel(const float* __restrict__ X, float* __restrict__ sqout) {
  int i = blockIdx.x * NTHR + threadIdx.x;
  const float4* x4 = (const float4*)(X + (size_t)i * DIM);
  float s = 0.f;
#pragma unroll
  for (int k = 0; k < DIM / 4; ++k) {
    float4 v = x4[k];
    s = fmaf(v.x, v.x, s); s = fmaf(v.y, v.y, s);
    s = fmaf(v.z, v.z, s); s = fmaf(v.w, v.w, s);
  }
  sqout[i] = s;
}

__global__ void knn_kernel(
    const float* __restrict__ X, const float* __restrict__ sqn,
    float* __restrict__ cand_val, int* __restrict__ cand_idx) {
  __shared__ float As[BM * LS];   // 17408 B
  __shared__ float Bs[BN * LS];   // 17408 B
  __shared__ float sqt[BN];

  const int tid = threadIdx.x;
  const int tx = tid & 15;
  const int ty = tid >> 4;
  const int ib = blockIdx.x >> 2;   // / JSPLIT
  const int jh = blockIdx.x & 3;    // % JSPLIT
  const int i0 = ib * BM;
  const int j0base = jh * JRANGE;

  // Stage A tile (BM x DIM) once: coalesced float4 loads. 1024 float4s.
  {
    const float4* src = (const float4*)(X + (size_t)i0 * DIM);
#pragma unroll
    for (int p = 0; p < (BM * DIM / 4) / NTHR; ++p) {
      int f4 = tid + NTHR * p;
      int r = f4 >> 4, c = f4 & 15;   // 16 float4 per row
      float4 v = src[f4];
      *(float4*)(&As[r * LS + c * 4]) = v;
    }
  }

  float bestv[TM];
  int besti[TM];
#pragma unroll
  for (int mk = 0; mk < TM; ++mk) { bestv[mk] = INFINITY; besti[mk] = 0x7fffffff; }

  for (int jt = 0; jt < NJT; ++jt) {
    const int j0 = j0base + jt * BN;
    __syncthreads();   // protect Bs from previous iteration's readers
    // Stage B tile (BN x DIM)
    {
      const float4* src = (const float4*)(X + (size_t)j0 * DIM);
#pragma unroll
      for (int p = 0; p < (BN * DIM / 4) / NTHR; ++p) {
        int f4 = tid + NTHR * p;
        int r = f4 >> 4, c = f4 & 15;
        float4 v = src[f4];
        *(float4*)(&Bs[r * LS + c * 4]) = v;
      }
      if (tid < BN) sqt[tid] = sqn[j0 + tid];
    }
    __syncthreads();

    float acc[TM][TN];
#pragma unroll
    for (int mk = 0; mk < TM; ++mk)
#pragma unroll
      for (int nk = 0; nk < TN; ++nk) acc[mk][nk] = 0.f;

#pragma unroll
    for (int d0 = 0; d0 < DIM; d0 += 4) {
      float4 a[TM], b[TN];
#pragma unroll
      for (int mk = 0; mk < TM; ++mk)
        a[mk] = *(const float4*)(&As[(ty + 16 * mk) * LS + d0]);
#pragma unroll
      for (int nk = 0; nk < TN; ++nk)
        b[nk] = *(const float4*)(&Bs[(tx + 16 * nk) * LS + d0]);
#pragma unroll
      for (int mk = 0; mk < TM; ++mk)
#pragma unroll
        for (int nk = 0; nk < TN; ++nk) {
          acc[mk][nk] = fmaf(a[mk].x, b[nk].x, acc[mk][nk]);
          acc[mk][nk] = fmaf(a[mk].y, b[nk].y, acc[mk][nk]);
          acc[mk][nk] = fmaf(a[mk].z, b[nk].z, acc[mk][nk]);
          acc[mk][nk] = fmaf(a[mk].w, b[nk].w, acc[mk][nk]);
        }
    }

    // Update running argmin (j visited in increasing order per thread).
#pragma unroll
    for (int nk = 0; nk < TN; ++nk) {
      const int j = j0 + tx + 16 * nk;
      const float sj = sqt[tx + 16 * nk];
#pragma unroll
      for (int mk = 0; mk < TM; ++mk) {
        const int irow = i0 + ty + 16 * mk;
        float v = fmaf(-2.f, acc[mk][nk], sj);
        if (j != irow && (v < bestv[mk] || (v == bestv[mk] && j < besti[mk]))) {
          bestv[mk] = v;
          besti[mk] = j;
        }
      }
    }
  }

  // Cross-thread reduction: row m = ty + 16*mk is owned by the 16 tx-threads.
  __syncthreads();
  float* rv = As;        // [BM][16] floats (4 KB, fits in As)
  int* ri = (int*)Bs;    // [BM][16] ints  (4 KB, fits in Bs)
#pragma unroll
  for (int mk = 0; mk < TM; ++mk) {
    int m = ty + 16 * mk;
    rv[m * 16 + tx] = bestv[mk];
    ri[m * 16 + tx] = besti[mk];
  }
  __syncthreads();
  if (tid < BM) {
    float bv = INFINITY;
    int bi = 0x7fffffff;
#pragma unroll
    for (int t = 0; t < 16; ++t) {
      float v = rv[tid * 16 + t];
      int ix = ri[tid * 16 + t];
      if (v < bv || (v == bv && ix < bi)) { bv = v; bi = ix; }
    }
    cand_val[(size_t)(i0 + tid) * JSPLIT + jh] = bv;
    cand_idx[(size_t)(i0 + tid) * JSPLIT + jh] = bi;
  }
}

__global__ void merge_kernel(const float* __restrict__ cand_val,
                             const int* __restrict__ cand_idx,
                             float* __restrict__ out) {
  int i = blockIdx.x * NTHR + threadIdx.x;
  float bv = INFINITY;
  int bi = 0x7fffffff;
#pragma unroll
  for (int s = 0; s < JSPLIT; ++s) {
    float v = cand_val[(size_t)i * JSPLIT + s];
    int ix = cand_idx[(size_t)i * JSPLIT + s];
    if (v < bv || (v == bv && ix < bi)) { bv = v; bi = ix; }
  }
  out[(size_t)i * NPTS + i] = 1.0f;   // self is always nearest (dist ~ 0)
  out[(size_t)i * NPTS + bi] = 1.0f;  // nearest other neighbor
}

extern "C" void kernel_launch(void* const* d_in, const int* in_sizes, int n_in,
                              void* d_out, int out_size, void* d_ws, size_t ws_size,
                              hipStream_t stream) {
  const float* X = (const float*)d_in[0];
  float* out = (float*)d_out;

  // Workspace layout: sq[N] | cand_val[N*JSPLIT] | cand_idx[N*JSPLIT]  (~576 KB)
  float* sq = (float*)d_ws;
  float* cand_val = sq + NPTS;
  int* cand_idx = (int*)(cand_val + (size_t)NPTS * JSPLIT);

  // 16384^2 floats = 67,108,864 float4 = 65536 blocks x 256 threads x 4 stores.
  zero_kernel<<<65536, NTHR, 0, stream>>>((floatx4*)out);
  sq_kernel<<<NPTS / NTHR, NTHR, 0, stream>>>(X, sq);
  knn_kernel<<<(NPTS / BM) * JSPLIT, NTHR, 0, stream>>>(X, sq, cand_val, cand_idx);
  merge_kernel<<<NPTS / NTHR, NTHR, 0, stream>>>(cand_val, cand_idx, out);
}